// Round 1
// baseline (491.597 us; speedup 1.0000x reference)
//
#include <hip/hip_runtime.h>
#include <hip/hip_bf16.h>
#include <stdint.h>

// GPT self-attention, B=4 S=2048 E=2048 D=2048. FP32 in/out, bf16 MFMA internally.
// Round-5: gemm core rewritten as the 256^2 / BK=64 / 8-wave "8-phase" schedule
// (T2+T3+T4+T5): K-split LDS halves (256x32 per half, 2 bufs = 128 KiB), one
// half-tile staged per phase via global_load_lds w16 with 6-half-tile lead,
// ONE counted s_waitcnt vmcnt(4) per K-tile (never 0), raw s_barrier pairs,
// lgkmcnt(0)+sched_barrier before the 16-MFMA cluster wrapped in s_setprio.

typedef unsigned short u16;
typedef unsigned int u32;
typedef __bf16 bf16x8 __attribute__((ext_vector_type(8)));
typedef float floatx4 __attribute__((ext_vector_type(4)));

#define DEVI __device__ __forceinline__

constexpr int Bn = 4, Sn = 2048, En = 2048, Dn = 2048;

DEVI u16 f2b(float f) {  // round-to-nearest-even f32 -> bf16
  union { float f; u32 u; } v; v.f = f;
  u32 r = v.u + 0x7FFFu + ((v.u >> 16) & 1u);
  return (u16)(r >> 16);
}

DEVI void cp16(const u16* g, u16* l) {  // async global->LDS, 16 B per lane
  __builtin_amdgcn_global_load_lds(
      (const __attribute__((address_space(1))) void*)g,
      (__attribute__((address_space(3))) void*)l, 16, 0, 0);
}

// ---- fp32 -> bf16 elementwise, n multiple of 2048; 8 elems/thread.
__global__ __launch_bounds__(256)
void cvt_kernel(const float* __restrict__ src, u16* __restrict__ dst, int n) {
  int i = (blockIdx.x * 256 + threadIdx.x) * 8;
  if (i >= n) return;
  float4 a = *(const float4*)&src[i];
  float4 b = *(const float4*)&src[i + 4];
  *(ushort4*)&dst[i]     = make_ushort4(f2b(a.x), f2b(a.y), f2b(a.z), f2b(a.w));
  *(ushort4*)&dst[i + 4] = make_ushort4(f2b(b.x), f2b(b.y), f2b(b.z), f2b(b.w));
}

// ============================ 8-phase GEMM core =============================
// C[m0..+256, n0..+256] += A[*,K] * Bt[*,K]^T (row-major, K contiguous), bf16,
// fp32 acc. 512 threads = 8 waves (2M x 4N); per-wave 128x64 out = acc[8][4].
// LDS (u16 elems): buf b (0/1) at b*32768; A half s at +s*8192; B at +16384+s*8192.
// Half = 256 rows x 32 cols, row = 64 B = 4 16B-groups; group g of row r stored
// at g ^ ((r>>1)&3)  -> fragment ds_read_b128 lands 2 lanes/bank (free).
// Stage stream per kt: [Ah0, Bh0, Ah1, Bh1]; phase p of kt m stages stream
// 4m+p+6 (lead 6): p0->(m+1,Ah1) p1->(m+1,Bh1) p2->(m+2,Ah0) p3->(m+2,Bh0).
// Slot legality: Ah0(m)/Bh0(m) last read in phases 4m,4m+1 -> overwrite issued
// at 4m+2/4m+3 after a barrier; Ah1/Bh1(m) last read 4m+2..3 -> overwritten at
// 4(m+1)+0/+1. Consumption: vmcnt(4) at end of kt m-1 leaves only streams
// 4m+4,4m+5 (2 half-tiles = 4 loads) in flight => kt m's 4 halves landed.
DEVI void gemm8(const u16* __restrict__ A, const u16* __restrict__ Bt,
                int lda, int ldb, int m0, int n0, int kEnd, u16* lds,
                floatx4 acc[8][4]) {
  const int tid = threadIdx.x;
  const int wave = tid >> 6, lane = tid & 63;
  const int wm = (wave >> 2) * 128, wn = (wave & 3) * 64;
  const int quad = lane >> 4, l16 = lane & 15;
  const int swe = (quad ^ ((l16 >> 1) & 3)) * 8;  // swizzled group, u16 elems
  const int nkt = kEnd >> 6;

  // staging coords: chunk c = (q*8+wave)*64 + lane, c in [0,1024); row=c>>2,
  // phys group c&3 holds logical group (c&3)^((row>>1)&3) (pre-swizzled src).
  int dstc[2];
  const u16 *Asp[2], *Bsp[2];
#pragma unroll
  for (int q = 0; q < 2; ++q) {
    int c0 = (q * 8 + wave) * 64;  // wave-uniform chunk base
    int c = c0 + lane;
    int sr = c >> 2;
    int sg = ((c & 3) ^ ((sr >> 1) & 3)) * 8;
    dstc[q] = c0 * 8;  // u16 elem offset of this issue's LDS base
    Asp[q] = A + (size_t)(m0 + sr) * lda + sg;
    Bsp[q] = Bt + (size_t)(n0 + sr) * ldb + sg;
  }
  // per-lane fragment read bases (u16 elems within a buffer)
  const int rbA = (wm + l16) * 32 + swe;
  const int rbB = 16384 + (wn + l16) * 32 + swe;

#define STAGE(ktu, isB, sh)                                                  \
  {                                                                          \
    int kc = (ktu) < nkt ? (ktu) : (nkt - 1); /* clamp src; dst keeps slot */ \
    int ks = (kc << 6) + (sh) * 32;                                          \
    int db = (((ktu) & 1) << 15) + (isB) * 16384 + (sh) * 8192;              \
    cp16(((isB) ? Bsp[0] : Asp[0]) + ks, &lds[db + dstc[0]]);                \
    cp16(((isB) ? Bsp[1] : Asp[1]) + ks, &lds[db + dstc[1]]);                \
  }

  // prologue: stream 0..5 = kt0 all 4 halves + kt1 {Ah0,Bh0}
  STAGE(0, 0, 0); STAGE(0, 1, 0); STAGE(0, 0, 1); STAGE(0, 1, 1);
  STAGE(1, 0, 0); STAGE(1, 1, 0);
  asm volatile("s_waitcnt vmcnt(4)" ::: "memory");  // kt0 landed; kt1 h0 in flight
  __builtin_amdgcn_s_barrier();

  for (int m = 0; m < nkt; ++m) {
    const int bofs = (m & 1) << 15;
    bf16x8 bf[4];  // B frags cached across the two cm-phases of each k-step
#pragma unroll
    for (int p = 0; p < 4; ++p) {
      const int s = p >> 1, cm = p & 1;
      bf16x8 af[4];
      const int abase = bofs + s * 8192 + rbA + cm * 2048;
#pragma unroll
      for (int i = 0; i < 4; ++i) af[i] = *(const bf16x8*)&lds[abase + i * 512];
      if (cm == 0) {
        const int bbase = bofs + s * 8192 + rbB;
#pragma unroll
        for (int j = 0; j < 4; ++j) bf[j] = *(const bf16x8*)&lds[bbase + j * 512];
      }
      if (p == 0)      { STAGE(m + 1, 0, 1); }
      else if (p == 1) { STAGE(m + 1, 1, 1); }
      else if (p == 2) { STAGE(m + 2, 0, 0); }
      else             { STAGE(m + 2, 1, 0); }
      __builtin_amdgcn_s_barrier();
      asm volatile("s_waitcnt lgkmcnt(0)" ::: "memory");
      __builtin_amdgcn_sched_barrier(0);  // rule 18: pin MFMA after the wait
      __builtin_amdgcn_s_setprio(1);
#pragma unroll
      for (int i = 0; i < 4; ++i)
#pragma unroll
        for (int j = 0; j < 4; ++j)
          acc[cm * 4 + i][j] = __builtin_amdgcn_mfma_f32_16x16x32_bf16(
              af[i], bf[j], acc[cm * 4 + i][j], 0, 0, 0);
      __builtin_amdgcn_s_setprio(0);
      if (p == 3) asm volatile("s_waitcnt vmcnt(4)" ::: "memory");  // next kt ready
      __builtin_amdgcn_s_barrier();
    }
  }
#undef STAGE
}

// ---- QKV projection: y = x @ W^T over all tokens passed (grid.y*256 of them).
// z=0->Q, z=1->K (both [t][d]), z=2->V transposed per batch (b = t>>11).
__global__ __launch_bounds__(512, 2)
void proj_kernel(const u16* __restrict__ x, const u16* __restrict__ Wq,
                 const u16* __restrict__ Wk, const u16* __restrict__ Wv,
                 u16* __restrict__ Q, u16* __restrict__ K, u16* __restrict__ Vt) {
  __shared__ __align__(16) u16 lds[65536];
  const int z = blockIdx.z;
  const u16* W = (z == 0) ? Wq : (z == 1) ? Wk : Wv;
  const int m0 = blockIdx.y * 256, n0 = blockIdx.x * 256;
  floatx4 acc[8][4] = {};
  gemm8(x, W, En, En, m0, n0, En, lds, acc);

  const int lane = threadIdx.x & 63, wave = threadIdx.x >> 6;
  const int wm = (wave >> 2) * 128, wn = (wave & 3) * 64;
  const int quad = lane >> 4, l16 = lane & 15;

  if (z < 2) {
    u16* dst = (z == 0) ? Q : K;
#pragma unroll
    for (int mi = 0; mi < 8; ++mi) {
      int t0 = m0 + wm + mi * 16 + quad * 4;  // token index
#pragma unroll
      for (int j = 0; j < 4; ++j) {
        int gn = n0 + wn + j * 16 + l16;
#pragma unroll
        for (int r = 0; r < 4; ++r)
          dst[(size_t)(t0 + r) * Dn + gn] = f2b(acc[mi][j][r]);
      }
    }
  } else {
#pragma unroll
    for (int mi = 0; mi < 8; ++mi) {
      int t0 = m0 + wm + mi * 16 + quad * 4;
      int b = t0 >> 11, s0 = t0 & (Sn - 1);  // 256-token tiles never straddle batches
#pragma unroll
      for (int j = 0; j < 4; ++j) {
        int gn = n0 + wn + j * 16 + l16;  // d index
        *(ushort4*)&Vt[((size_t)b * Dn + gn) * Sn + s0] =
            make_ushort4(f2b(acc[mi][j][0]), f2b(acc[mi][j][1]),
                         f2b(acc[mi][j][2]), f2b(acc[mi][j][3]));
      }
    }
  }
}

// ---- scores = Q_b @ K_b^T / sqrt(D), causal; z = batch. Skipped tiles -> -1e30.
__global__ __launch_bounds__(512, 2)
void scores_kernel(const u16* __restrict__ Q, const u16* __restrict__ K,
                   float* __restrict__ Sc) {
  const int b = blockIdx.z;
  const int m0 = blockIdx.y * 256, n0 = blockIdx.x * 256;
  float* C = Sc + (size_t)b * Sn * Sn;
  if (n0 > m0 + 255) {
    const float4 f = make_float4(-1e30f, -1e30f, -1e30f, -1e30f);
    for (int idx = threadIdx.x; idx < 256 * 64; idx += 512) {
      int r = idx >> 6, c4 = (idx & 63) << 2;
      *(float4*)&C[(size_t)(m0 + r) * Sn + n0 + c4] = f;
    }
    return;
  }
  __shared__ __align__(16) u16 lds[65536];
  floatx4 acc[8][4] = {};
  gemm8(Q + (size_t)b * Sn * Dn, K + (size_t)b * Sn * Dn, Dn, Dn, m0, n0, Dn,
        lds, acc);

  const float inv_scale = 0.022097086912079608f;  // 1/sqrt(2048)
  const int lane = threadIdx.x & 63, wave = threadIdx.x >> 6;
  const int wm = (wave >> 2) * 128, wn = (wave & 3) * 64;
  const int quad = lane >> 4, l16 = lane & 15;
#pragma unroll
  for (int mi = 0; mi < 8; ++mi) {
    int gm0 = m0 + wm + mi * 16 + quad * 4;
#pragma unroll
    for (int j = 0; j < 4; ++j) {
      int gn = n0 + wn + j * 16 + l16;
#pragma unroll
      for (int r = 0; r < 4; ++r) {
        float v = acc[mi][j][r] * inv_scale;
        if (gn > gm0 + r) v = -1e30f;
        C[(size_t)(gm0 + r) * Sn + gn] = v;
      }
    }
  }
}

// ---- row softmax over 2048 fp32; write attn bf16 in-place (u16 pitch 2*Sn).
__global__ __launch_bounds__(256)
void softmax_kernel(float* __restrict__ Sc) {
  float* sr = Sc + (size_t)blockIdx.x * Sn;
  const int t = threadIdx.x;
  float4 v0 = ((const float4*)sr)[t];
  float4 v1 = ((const float4*)sr)[t + 256];
  float m = fmaxf(fmaxf(fmaxf(v0.x, v0.y), fmaxf(v0.z, v0.w)),
                  fmaxf(fmaxf(v1.x, v1.y), fmaxf(v1.z, v1.w)));
#pragma unroll
  for (int off = 32; off; off >>= 1) m = fmaxf(m, __shfl_xor(m, off));
  __shared__ float redm[4], reds[4];
  if ((t & 63) == 0) redm[t >> 6] = m;
  __syncthreads();
  m = fmaxf(fmaxf(redm[0], redm[1]), fmaxf(redm[2], redm[3]));

  float e[8];
  e[0] = __expf(v0.x - m); e[1] = __expf(v0.y - m);
  e[2] = __expf(v0.z - m); e[3] = __expf(v0.w - m);
  e[4] = __expf(v1.x - m); e[5] = __expf(v1.y - m);
  e[6] = __expf(v1.z - m); e[7] = __expf(v1.w - m);
  float s = ((e[0] + e[1]) + (e[2] + e[3])) + ((e[4] + e[5]) + (e[6] + e[7]));
#pragma unroll
  for (int off = 32; off; off >>= 1) s += __shfl_xor(s, off);
  if ((t & 63) == 0) reds[t >> 6] = s;
  __syncthreads();
  s = (reds[0] + reds[1]) + (reds[2] + reds[3]);
  float inv = 1.0f / s;

  u16* ar = (u16*)sr;  // all global reads above; in-place bf16 write is safe
  *(ushort4*)&ar[t * 4] =
      make_ushort4(f2b(e[0] * inv), f2b(e[1] * inv), f2b(e[2] * inv), f2b(e[3] * inv));
  *(ushort4*)&ar[(t + 256) * 4] =
      make_ushort4(f2b(e[4] * inv), f2b(e[5] * inv), f2b(e[6] * inv), f2b(e[7] * inv));
}

// ---- out_b = attn @ V via Vt; z = batch; K-loop truncated at diagonal. FP32 out.
__global__ __launch_bounds__(512, 2)
void pv_kernel(const float* __restrict__ Sc, const u16* __restrict__ Vt,
               float* __restrict__ out) {
  const int b = blockIdx.z;
  const int m0 = blockIdx.y * 256, n0 = blockIdx.x * 256;
  __shared__ __align__(16) u16 lds[65536];
  floatx4 acc[8][4] = {};
  const u16* P = (const u16*)(Sc + (size_t)b * Sn * Sn);  // bf16 attn, pitch 2*Sn
  gemm8(P, Vt + (size_t)b * Dn * Sn, 2 * Sn, Sn, m0, n0, m0 + 256, lds, acc);

  const int lane = threadIdx.x & 63, wave = threadIdx.x >> 6;
  const int wm = (wave >> 2) * 128, wn = (wave & 3) * 64;
  const int quad = lane >> 4, l16 = lane & 15;
  float* ob = out + (size_t)b * Sn * Dn;
#pragma unroll
  for (int mi = 0; mi < 8; ++mi) {
    int gm0 = m0 + wm + mi * 16 + quad * 4;
#pragma unroll
    for (int j = 0; j < 4; ++j) {
      int gn = n0 + wn + j * 16 + l16;
#pragma unroll
      for (int r = 0; r < 4; ++r)
        ob[(size_t)(gm0 + r) * Dn + gn] = acc[mi][j][r];
    }
  }
}

extern "C" void kernel_launch(void* const* d_in, const int* in_sizes, int n_in,
                              void* d_out, int out_size, void* d_ws, size_t ws_size,
                              hipStream_t stream) {
  const float* x  = (const float*)d_in[0];   // setup_inputs order: x, Wk, Wq, Wv (fp32)
  const float* Wk = (const float*)d_in[1];
  const float* Wq = (const float*)d_in[2];
  const float* Wv = (const float*)d_in[3];
  float* out = (float*)d_out;

  dim3 blk(256), blk5(512);
  const int nW = Dn * En;                    // 4M elems per weight
  const size_t MiB = 1ull << 20;

  if (ws_size >= 184 * MiB) {
    // ---- fused path: Wqb|Wkb|Wvb | xb(all) | K(all) | Vt(all) | Sc(all fp32)
    u16* Wqb = (u16*)d_ws;
    u16* Wkb = Wqb + (size_t)nW;
    u16* Wvb = Wkb + (size_t)nW;
    u16* xb  = Wvb + (size_t)nW;             // [8192][2048]
    u16* Kall = xb + (size_t)Bn * Sn * En;   // [8192][2048]
    u16* Vtall = Kall + (size_t)Bn * Sn * Dn;  // [b][d][s]
    float* Sc = (float*)(Vtall + (size_t)Bn * Dn * Sn);  // [b][s][s]
    u16* Qall = (u16*)out;                   // 32 MiB of the 64 MiB out; pv overwrites

    cvt_kernel<<<nW / 2048, blk, 0, stream>>>(Wq, Wqb, nW);
    cvt_kernel<<<nW / 2048, blk, 0, stream>>>(Wk, Wkb, nW);
    cvt_kernel<<<nW / 2048, blk, 0, stream>>>(Wv, Wvb, nW);
    cvt_kernel<<<(Bn * Sn * En) / 2048, blk, 0, stream>>>(x, xb, Bn * Sn * En);
    proj_kernel<<<dim3(Dn / 256, (Bn * Sn) / 256, 3), blk5, 0, stream>>>(
        xb, Wqb, Wkb, Wvb, Qall, Kall, Vtall);
    scores_kernel<<<dim3(Sn / 256, Sn / 256, Bn), blk5, 0, stream>>>(Qall, Kall, Sc);
    softmax_kernel<<<dim3(Bn * Sn), blk, 0, stream>>>(Sc);
    pv_kernel<<<dim3(Dn / 256, Sn / 256, Bn), blk5, 0, stream>>>(Sc, Vtall, out);
  } else {
    // ---- sequential fallback (56 MiB): Wqb|Wkb|Wvb | Sc (xb aliased) | Kb | Vtb
    u16* Wqb = (u16*)d_ws;
    u16* Wkb = Wqb + (size_t)nW;
    u16* Wvb = Wkb + (size_t)nW;
    float* Sc = (float*)(Wvb + (size_t)nW);
    u16* xb  = (u16*)Sc;                     // dead once scores_kernel runs
    u16* Kb  = (u16*)(Sc + (size_t)Sn * Sn);
    u16* Vtb = Kb + (size_t)Sn * Dn;

    cvt_kernel<<<nW / 2048, blk, 0, stream>>>(Wq, Wqb, nW);
    cvt_kernel<<<nW / 2048, blk, 0, stream>>>(Wk, Wkb, nW);
    cvt_kernel<<<nW / 2048, blk, 0, stream>>>(Wv, Wvb, nW);
    for (int b = 0; b < Bn; ++b) {
      const float* xf = x + (size_t)b * Sn * En;
      float* outb = out + (size_t)b * Sn * Dn;
      u16* Qb = (u16*)outb;                  // bf16 Q in out_b's region; pv overwrites
      cvt_kernel<<<(Sn * En) / 2048, blk, 0, stream>>>(xf, xb, Sn * En);
      proj_kernel<<<dim3(Dn / 256, Sn / 256, 3), blk5, 0, stream>>>(xb, Wqb, Wkb, Wvb,
                                                                    Qb, Kb, Vtb);
      scores_kernel<<<dim3(Sn / 256, Sn / 256, 1), blk5, 0, stream>>>(Qb, Kb, Sc);
      softmax_kernel<<<dim3(Sn), blk, 0, stream>>>(Sc);
      pv_kernel<<<dim3(Dn / 256, Sn / 256, 1), blk5, 0, stream>>>(Sc, Vtb, outb);
    }
  }
}